// Round 11
// baseline (203.384 us; speedup 1.0000x reference)
//
#include <hip/hip_runtime.h>

// EOQLinear: int4-quantized GEMV.
//   out[n] = sum_b scales[n,b] * sum_{q in block b} w_int[n,q] * x[q]
// packed_w[n,j] is an int32 in [0,256): low nibble -> k=2j, high nibble -> k=2j+1, -8.
//
// DTYPE NOTE (round-1): harness stages the reference's float16 tensors as FLOAT32.
//
// ROUND-11. Evidence so far: four structures (compiler-scheduled row/wave,
// 4 rows/wave 4x MLP, VGPR depth-8 prefetch ring) ALL pin at kernel ~54-55 us
// (2.4 TB/s HBM), while the round-8 probe's L3-warm passes consumed 6.3 TB/s
// logical with identical code -> consumption fast, HBM delivery stuck.
// In-flight-bytes theory dead; fine channel aliasing dead (round-6 stagger
// neutral). Shared trait of all four: thousands of sparse per-row streams
// covering the whole 128 MiB at once (1 KiB touched per 16 KiB) -> DRAM
// page/bank thrash (every access pays a row-activate). The 6.9 TB/s fills and
// d2d restores sweep a narrow moving window instead.
//
// CHANGE: linear-sweep decomposition. 8192 waves; at step i wave W reads flat
// 1 KiB chunk c = i*N + W -> the device reads a dense 8 MiB window advancing
// sequentially, like a fill. Chunk c belongs entirely to row c/16 (pos c&15);
// each lane's 8 weights share one quant block. Per step: dequant-dot, *scale,
// wave-reduce, lane0 atomicAdd(&out[row]) (16 adds/row total, fp32). d_out is
// poisoned 0xAA -> hipMemsetAsync zero first (capture-legal, every call).

__global__ __launch_bounds__(256, 4)
void eoq_gemv_sweep(const float* __restrict__ x,
                    const int* __restrict__ packed_w,
                    const float* __restrict__ scales,
                    float* __restrict__ out,
                    int N, int steps, int cpShift, int cpMask,
                    int sShift, int blocksPerRow)
{
    const int lane = threadIdx.x & 63;
    const int W    = blockIdx.x * 4 + (threadIdx.x >> 6);   // wave id in [0, N)

    const int4*   __restrict__ wflat = reinterpret_cast<const int4*>(packed_w);
    const float4* __restrict__ x4p   = reinterpret_cast<const float4*>(x);

    #pragma unroll 4
    for (int i = 0; i < steps; ++i) {
        const int c   = i * N + W;          // flat 1 KiB chunk index (dense/step)
        const int row = c >> cpShift;       // owning output row
        const int pos = c & cpMask;         // chunk position within the row

        const int4   w4 = wflat[(size_t)c * 64 + lane];
        const float4 xa = x4p[(pos << 7) + (lane << 1)];
        const float4 xb = x4p[(pos << 7) + (lane << 1) + 1];
        const float  s  = scales[(size_t)row * blocksPerRow
                                 + (((pos << 6) + lane) >> sShift)];

        const unsigned w0 = (unsigned)w4.x;
        const unsigned w1 = (unsigned)w4.y;
        const unsigned w2 = (unsigned)w4.z;
        const unsigned w3 = (unsigned)w4.w;

        float part = 0.f;
        part = fmaf((float)(int)(w0 & 0xFu) - 8.f, xa.x, part);
        part = fmaf((float)(int)(w0 >> 4)   - 8.f, xa.y, part);
        part = fmaf((float)(int)(w1 & 0xFu) - 8.f, xa.z, part);
        part = fmaf((float)(int)(w1 >> 4)   - 8.f, xa.w, part);
        part = fmaf((float)(int)(w2 & 0xFu) - 8.f, xb.x, part);
        part = fmaf((float)(int)(w2 >> 4)   - 8.f, xb.y, part);
        part = fmaf((float)(int)(w3 & 0xFu) - 8.f, xb.z, part);
        part = fmaf((float)(int)(w3 >> 4)   - 8.f, xb.w, part);

        float v = part * s;
        #pragma unroll
        for (int off = 32; off > 0; off >>= 1)
            v += __shfl_down(v, off, 64);

        if (lane == 0) atomicAdd(&out[row], v);
    }
}

// Generic fallback (round-7/10 structure): 1 row/wave, plain loop.
__global__ __launch_bounds__(256, 2)
void eoq_gemv_generic(const float* __restrict__ x,
                      const int* __restrict__ packed_w,
                      const float* __restrict__ scales,
                      float* __restrict__ out,
                      int N, int halfK, int iters, int sShift, int blocksPerRow)
{
    const int lane = threadIdx.x & 63;
    const int wave = threadIdx.x >> 6;
    const int row  = blockIdx.x * 4 + wave;
    if (row >= N) return;

    const int4*   __restrict__ w4p =
        reinterpret_cast<const int4*>(packed_w + (size_t)row * halfK);
    const float4* __restrict__ x4p = reinterpret_cast<const float4*>(x);
    const float*  __restrict__ srow = scales + (size_t)row * blocksPerRow;

    float acc = 0.f;
    #pragma unroll 2
    for (int it = 0; it < iters; ++it) {
        const int j4 = (it << 6) + lane;
        const int4   w4 = w4p[j4];
        const float4 xa = x4p[2 * j4];
        const float4 xb = x4p[2 * j4 + 1];
        const float  s  = srow[j4 >> sShift];

        const unsigned w0 = (unsigned)w4.x;
        const unsigned w1 = (unsigned)w4.y;
        const unsigned w2 = (unsigned)w4.z;
        const unsigned w3 = (unsigned)w4.w;

        float part = 0.f;
        part = fmaf((float)(int)(w0 & 0xFu) - 8.f, xa.x, part);
        part = fmaf((float)(int)(w0 >> 4)   - 8.f, xa.y, part);
        part = fmaf((float)(int)(w1 & 0xFu) - 8.f, xa.z, part);
        part = fmaf((float)(int)(w1 >> 4)   - 8.f, xa.w, part);
        part = fmaf((float)(int)(w2 & 0xFu) - 8.f, xb.x, part);
        part = fmaf((float)(int)(w2 >> 4)   - 8.f, xb.y, part);
        part = fmaf((float)(int)(w3 & 0xFu) - 8.f, xb.z, part);
        part = fmaf((float)(int)(w3 >> 4)   - 8.f, xb.w, part);
        acc = fmaf(s, part, acc);
    }

    #pragma unroll
    for (int off = 32; off > 0; off >>= 1)
        acc += __shfl_down(acc, off, 64);

    if (lane == 0) out[row] = acc;
}

extern "C" void kernel_launch(void* const* d_in, const int* in_sizes, int n_in,
                              void* d_out, int out_size, void* d_ws, size_t ws_size,
                              hipStream_t stream) {
    const float* x      = (const float*)d_in[0];
    const int*   pw     = (const int*)d_in[1];
    const float* scales = (const float*)d_in[2];
    float*       out    = (float*)d_out;

    const int K     = in_sizes[0];         // 8192
    const int halfK = K >> 1;              // 4096
    const int N     = in_sizes[1] / halfK; // 8192
    const int blocksPerRow = in_sizes[2] / N;    // K/QB = 64

    const int qhalf = halfK / blocksPerRow;      // QB/2 (pow2)
    int qhalfShift = 0;
    while ((1 << qhalfShift) < qhalf) ++qhalfShift;
    const int sShift = qhalfShift - 2;           // int4-idx within row -> qblock

    const int chunksPerRow = halfK >> 8;         // 1 KiB chunks per row (16)
    int cpShift = 0;
    while ((1 << cpShift) < chunksPerRow) ++cpShift;

    const bool sweepOK =
        (halfK % 256 == 0) &&                    // whole chunks per row
        ((1 << cpShift) == chunksPerRow) &&      // pow2 chunk count
        ((1 << qhalfShift) == qhalf) &&          // pow2 qblock
        (sShift >= 0) && (N % 4 == 0);

    if (sweepOK) {
        hipMemsetAsync(d_out, 0, (size_t)out_size * sizeof(float), stream);
        dim3 grid(N / 4), block(256);            // one wave-slot per row
        eoq_gemv_sweep<<<grid, block, 0, stream>>>(
            x, pw, scales, out, N, chunksPerRow, cpShift, chunksPerRow - 1,
            sShift, blocksPerRow);
    } else {
        dim3 grid((N + 3) / 4), block(256);
        eoq_gemv_generic<<<grid, block, 0, stream>>>(
            x, pw, scales, out, N, halfK, chunksPerRow, sShift, blocksPerRow);
    }
}

// Round 12
// 194.397 us; speedup vs baseline: 1.0462x; 1.0462x over previous
//
#include <hip/hip_runtime.h>

// EOQLinear: int4-quantized GEMV.
//   out[n] = sum_b scales[n,b] * sum_{q in block b} w_int[n,q] * x[q]
// packed_w[n,j] is an int32 in [0,256): low nibble -> k=2j, high nibble -> k=2j+1, -8.
//
// DTYPE NOTE (round-1): harness stages the reference's float16 tensors as FLOAT32.
//
// ROUND-12. Session evidence: five structures (compiler-scheduled 1 row/wave,
// 4 rows/wave 4x-MLP, VGPR depth-8 prefetch ring, linear device-wide sweep)
// ALL pin at kernel ~54-60 us = 2.35-2.4 TB/s demand-read, while the same code
// consumes 6.2 TB/s when L3-resident (round-8 warm passes) and fills write at
// 6.9 TB/s. Pattern, MLP, occupancy, and pipelining theories are all falsified.
// Remaining mechanism: demand reads ALLOCATE into L2/L3 and the allocation/
// victim path throttles HBM fills at ~2.4 TB/s. __builtin_nontemporal_load
// was never actually tested: round-4 failed at compile (HIP int4), round-5's
// crash was the scales-stride OOB bug (fixed in round 6), and nt was removed
// in the same edit — mis-attribution. This round: round-6's known-good
// structure + nt weight loads (clang ext_vector_type(4), compiles per round 5).
// One variable changed.
//
// Layout: one 64-lane wave per output row, 4 rows per 256-thread block
// (2048 blocks, zero LDS). Weights: nontemporal 16 B loads, 1 KiB contiguous
// per wave-instruction. x: 32 KB cache-resident, 2x float4 per iter (cached).
// Scale: one per 4-int chunk (srow[j4>>sShift]); fp32 acc, butterfly reduce.

typedef int   iv4 __attribute__((ext_vector_type(4)));

#define WAVES_PER_BLOCK 4

__global__ __launch_bounds__(256, 4)
void eoq_gemv_kernel(const float* __restrict__ x,
                     const int* __restrict__ packed_w,
                     const float* __restrict__ scales,
                     float* __restrict__ out,
                     int N, int halfK, int iters, int sShift, int blocksPerRow)
{
    const int lane = threadIdx.x & 63;
    const int wave = threadIdx.x >> 6;
    const int row  = blockIdx.x * WAVES_PER_BLOCK + wave;
    if (row >= N) return;

    const iv4*    __restrict__ w4p =
        reinterpret_cast<const iv4*>(packed_w + (size_t)row * halfK);
    const float4* __restrict__ x4p = reinterpret_cast<const float4*>(x);
    const float*  __restrict__ srow = scales + (size_t)row * blocksPerRow;

    float acc = 0.f;

    #pragma unroll 4
    for (int it = 0; it < iters; ++it) {
        const int j4 = (it << 6) + lane;            // 16B-chunk index in the row
        const iv4    w4 = __builtin_nontemporal_load(&w4p[j4]);  // no-allocate stream
        const float4 xa = x4p[2 * j4];              // x[8*j4   .. 8*j4+3] (cached)
        const float4 xb = x4p[2 * j4 + 1];          // x[8*j4+4 .. 8*j4+7]
        const float  s  = srow[j4 >> sShift];       // quant-block scale

        const unsigned w0 = (unsigned)w4.x;
        const unsigned w1 = (unsigned)w4.y;
        const unsigned w2 = (unsigned)w4.z;
        const unsigned w3 = (unsigned)w4.w;

        float part = 0.f;
        part = fmaf((float)(int)(w0 & 0xFu) - 8.f, xa.x, part);
        part = fmaf((float)(int)(w0 >> 4)   - 8.f, xa.y, part);
        part = fmaf((float)(int)(w1 & 0xFu) - 8.f, xa.z, part);
        part = fmaf((float)(int)(w1 >> 4)   - 8.f, xa.w, part);
        part = fmaf((float)(int)(w2 & 0xFu) - 8.f, xb.x, part);
        part = fmaf((float)(int)(w2 >> 4)   - 8.f, xb.y, part);
        part = fmaf((float)(int)(w3 & 0xFu) - 8.f, xb.z, part);
        part = fmaf((float)(int)(w3 >> 4)   - 8.f, xb.w, part);
        acc = fmaf(s, part, acc);
    }

    // wave-64 butterfly reduction
    #pragma unroll
    for (int off = 32; off > 0; off >>= 1)
        acc += __shfl_down(acc, off, 64);

    if (lane == 0) out[row] = acc;
}

extern "C" void kernel_launch(void* const* d_in, const int* in_sizes, int n_in,
                              void* d_out, int out_size, void* d_ws, size_t ws_size,
                              hipStream_t stream) {
    const float* x      = (const float*)d_in[0];
    const int*   pw     = (const int*)d_in[1];
    const float* scales = (const float*)d_in[2];
    float*       out    = (float*)d_out;

    const int K     = in_sizes[0];         // 8192
    const int halfK = K >> 1;              // 4096
    const int N     = in_sizes[1] / halfK; // 8192
    const int blocksPerRow = in_sizes[2] / N;    // K/QB = 64

    // packed ints per quant block = QB/2 = halfK/blocksPerRow (pow2);
    // sShift: 16B-chunk index -> quant-block index = log2(QB/2) - 2 (QB=128 -> 4)
    const int qhalf = halfK / blocksPerRow;
    int qhalfShift = 0;
    while ((1 << qhalfShift) < qhalf) ++qhalfShift;
    const int sShift = qhalfShift - 2;

    const int iters = halfK >> 8;          // 16B-chunk steps per row (16)

    dim3 grid((N + WAVES_PER_BLOCK - 1) / WAVES_PER_BLOCK), block(256);
    eoq_gemv_kernel<<<grid, block, 0, stream>>>(x, pw, scales, out,
                                                N, halfK, iters, sShift, blocksPerRow);
}